// Round 2
// baseline (2262.996 us; speedup 1.0000x reference)
//
#include <hip/hip_runtime.h>
#include <math.h>

#define EPSQ 1e-5f
#define TOK 8192
#define DM 2048
#define DF 8192
#define NW (DM*DF)

typedef float f32x4 __attribute__((ext_vector_type(4)));
typedef __bf16 bf16x8 __attribute__((ext_vector_type(8)));
typedef __bf16 bf16x4 __attribute__((ext_vector_type(4)));

// ---- fixed workspace layout (bytes) ----
#define OFF_DSUM 0ull                                // 3 doubles
#define OFF_SX   (4ull<<10)                          // 8192 f32
#define OFF_SH   (40ull<<10)                         // 8192 f32
#define OFF_XQ   (1ull<<20)                          // 32MB bf16 [8192][2048]
#define OFF_WGQ  (OFF_XQ  + (32ull<<20))             // 32MB bf16 [8192][2048]
#define OFF_WUQ  (OFF_WGQ + (32ull<<20))             // 32MB
#define OFF_WDQ  (OFF_WUQ + (32ull<<20))             // 32MB bf16 [2048][8192]
#define FIXED_END (OFF_WDQ + (32ull<<20))            // 129MB
// strip region (after FIXED_END): h fp32 [S][8192] + hq bf16 [S][8192]

#define GLL(gp, lp) __builtin_amdgcn_global_load_lds( \
    (const __attribute__((address_space(1))) unsigned int*)(gp), \
    (__attribute__((address_space(3))) unsigned int*)(lp), 16, 0, 0)

// ---- |w| sum (for absmean scale), double-precision total ----
__global__ void k_wabs(const float* __restrict__ w, double* __restrict__ dsum, int n4) {
  const f32x4* w4 = (const f32x4*)w;
  float s = 0.f;
  for (int i = blockIdx.x * blockDim.x + threadIdx.x; i < n4; i += gridDim.x * blockDim.x) {
    f32x4 v = w4[i];
    s += fabsf(v.x) + fabsf(v.y) + fabsf(v.z) + fabsf(v.w);
  }
  __shared__ float red[256];
  red[threadIdx.x] = s; __syncthreads();
  for (int o = 128; o > 0; o >>= 1) {
    if (threadIdx.x < o) red[threadIdx.x] += red[threadIdx.x + o];
    __syncthreads();
  }
  if (threadIdx.x == 0) atomicAdd(dsum, (double)red[0]);
}

// ---- ternary-quantize weights -> bf16 {-1,0,1} ----
__global__ void k_quant_w(const float* __restrict__ w, __bf16* __restrict__ wq,
                          const double* __restrict__ dsum, int n4) {
  float scale = (float)(*dsum / (double)NW) + EPSQ;
  const f32x4* w4 = (const f32x4*)w;
  for (int i = blockIdx.x * blockDim.x + threadIdx.x; i < n4; i += gridDim.x * blockDim.x) {
    f32x4 v = w4[i];
    bf16x4 o;
#pragma unroll
    for (int c = 0; c < 4; c++) {
      float q = rintf(v[c] / scale);
      q = fminf(1.f, fmaxf(-1.f, q));
      o[c] = (__bf16)q;
    }
    *(bf16x4*)&wq[(size_t)i * 4] = o;
  }
}

// ---- per-token int8 quantize x -> bf16 integer values + scale ----
__global__ void k_quant_x(const float* __restrict__ x, __bf16* __restrict__ xq,
                          float* __restrict__ sx) {
  const int row = blockIdx.x;
  const int tid = threadIdx.x;
  const f32x4* xr = (const f32x4*)(x + (size_t)row * DM);
  f32x4 v0 = xr[tid * 2], v1 = xr[tid * 2 + 1];
  float m = 0.f;
#pragma unroll
  for (int c = 0; c < 4; c++) m = fmaxf(m, fmaxf(fabsf(v0[c]), fabsf(v1[c])));
  __shared__ float red[256];
  red[tid] = m; __syncthreads();
  for (int o = 128; o > 0; o >>= 1) {
    if (tid < o) red[tid] = fmaxf(red[tid], red[tid + o]);
    __syncthreads();
  }
  float sc = fmaxf(red[0], EPSQ) / 127.f;
  if (tid == 0) sx[row] = sc;
  bf16x8 o;
#pragma unroll
  for (int c = 0; c < 4; c++) {
    float q0 = fminf(127.f, fmaxf(-128.f, rintf(v0[c] / sc)));
    float q1 = fminf(127.f, fmaxf(-128.f, rintf(v1[c] / sc)));
    o[c] = (__bf16)q0; o[c + 4] = (__bf16)q1;
  }
  *(bf16x8*)&xq[(size_t)row * DM + tid * 8] = o;
}

// ---- per-row max + quantize h (fp32, strip-local) -> bf16 int values + scale ----
__global__ void k_hquant(const float* __restrict__ h, __bf16* __restrict__ hq,
                         float* __restrict__ sh) {
  const int row = blockIdx.x;
  const int tid = threadIdx.x;
  const f32x4* hr = (const f32x4*)(h + (size_t)row * DF);
  f32x4 v[8];
  float m = 0.f;
#pragma unroll
  for (int j = 0; j < 8; j++) {
    v[j] = hr[tid * 8 + j];
#pragma unroll
    for (int c = 0; c < 4; c++) m = fmaxf(m, fabsf(v[j][c]));
  }
  __shared__ float red[256];
  red[tid] = m; __syncthreads();
  for (int o = 128; o > 0; o >>= 1) {
    if (tid < o) red[tid] = fmaxf(red[tid], red[tid + o]);
    __syncthreads();
  }
  float sc = fmaxf(red[0], EPSQ) / 127.f;
  if (tid == 0) sh[row] = sc;
#pragma unroll
  for (int jj = 0; jj < 4; jj++) {
    bf16x8 o;
#pragma unroll
    for (int c = 0; c < 4; c++) {
      float q0 = fminf(127.f, fmaxf(-128.f, rintf(v[jj * 2][c] / sc)));
      float q1 = fminf(127.f, fmaxf(-128.f, rintf(v[jj * 2 + 1][c] / sc)));
      o[c] = (__bf16)q0; o[c + 4] = (__bf16)q1;
    }
    *(bf16x8*)&hq[(size_t)row * DF + tid * 32 + jj * 8] = o;
  }
}

// ---- MFMA GEMM, both operands K-major: C[m,n] = (sum_k A[m,k]*B[n,k]) * rowscale[m] * sw ----
// DUAL=1: two B operands, epilogue h = sigmoid(g)*u
template<int DUAL>
__global__ __launch_bounds__(256)
void k_gemm(const __bf16* __restrict__ A, const __bf16* __restrict__ B0,
            const __bf16* __restrict__ B1, float* __restrict__ C,
            const float* __restrict__ rowscale,
            const double* __restrict__ dsum0, const double* __restrict__ dsum1,
            int N, int K) {
  const float sw0 = (float)(*dsum0 / (double)NW) + EPSQ;
  float sw1 = 0.f;
  if constexpr (DUAL) sw1 = (float)(*dsum1 / (double)NW) + EPSQ;

  __shared__ __align__(16) __bf16 sA[128 * 32];
  __shared__ __align__(16) __bf16 sB0[128 * 32];
  __shared__ __align__(16) __bf16 sB1[DUAL ? 128 * 32 : 8];

  const int tid = threadIdx.x;
  const int wv = tid >> 6;
  const int lane = tid & 63;
  const int wm = wv >> 1, wn = wv & 1;
  const int lr = lane & 15;
  const int lkb = (lane >> 4) * 8;

  const int m0 = blockIdx.y * 128;
  const int n0 = blockIdx.x * 128;

  const int srow = tid >> 2;
  const int scol = (tid & 3) * 8;
  const int ldsw = wv * 512;  // wave-uniform LDS staging base (elements)

  f32x4 acc0[4][4];
  f32x4 acc1[DUAL ? 4 : 1][DUAL ? 4 : 1];
  const f32x4 z4 = {0.f, 0.f, 0.f, 0.f};
#pragma unroll
  for (int i = 0; i < 4; i++)
#pragma unroll
    for (int j = 0; j < 4; j++) {
      acc0[i][j] = z4;
      if constexpr (DUAL) acc1[i][j] = z4;
    }

  const __bf16* gA = A + (size_t)(m0 + srow) * K + scol;
  const __bf16* gB0 = B0 + (size_t)(n0 + srow) * K + scol;
  const __bf16* gB1 = nullptr;
  if constexpr (DUAL) gB1 = B1 + (size_t)(n0 + srow) * K + scol;
  const size_t rstep = (size_t)64 * K;

  for (int k0 = 0; k0 < K; k0 += 32) {
    GLL(gA + k0, &sA[ldsw]);
    GLL(gA + k0 + rstep, &sA[2048 + ldsw]);
    GLL(gB0 + k0, &sB0[ldsw]);
    GLL(gB0 + k0 + rstep, &sB0[2048 + ldsw]);
    if constexpr (DUAL) {
      GLL(gB1 + k0, &sB1[ldsw]);
      GLL(gB1 + k0 + rstep, &sB1[2048 + ldsw]);
    }
    __syncthreads();

    bf16x8 af[4], bf0[4], bf1[4];
#pragma unroll
    for (int m = 0; m < 4; m++)
      af[m] = *(const bf16x8*)&sA[(wm * 64 + m * 16 + lr) * 32 + lkb];
#pragma unroll
    for (int n = 0; n < 4; n++)
      bf0[n] = *(const bf16x8*)&sB0[(wn * 64 + n * 16 + lr) * 32 + lkb];
    if constexpr (DUAL) {
#pragma unroll
      for (int n = 0; n < 4; n++)
        bf1[n] = *(const bf16x8*)&sB1[(wn * 64 + n * 16 + lr) * 32 + lkb];
    }
#pragma unroll
    for (int m = 0; m < 4; m++)
#pragma unroll
      for (int n = 0; n < 4; n++) {
        acc0[m][n] = __builtin_amdgcn_mfma_f32_16x16x32_bf16(af[m], bf0[n], acc0[m][n], 0, 0, 0);
        if constexpr (DUAL)
          acc1[m][n] = __builtin_amdgcn_mfma_f32_16x16x32_bf16(af[m], bf1[n], acc1[m][n], 0, 0, 0);
      }
    __syncthreads();
  }

  // epilogue: C/D layout col = lane&15, row = (lane>>4)*4 + j
  float rs[4][4];
#pragma unroll
  for (int m = 0; m < 4; m++)
#pragma unroll
    for (int j = 0; j < 4; j++)
      rs[m][j] = rowscale[m0 + wm * 64 + m * 16 + (lane >> 4) * 4 + j];

#pragma unroll
  for (int m = 0; m < 4; m++)
#pragma unroll
    for (int n = 0; n < 4; n++)
#pragma unroll
      for (int j = 0; j < 4; j++) {
        int row = m0 + wm * 64 + m * 16 + (lane >> 4) * 4 + j;
        int col = n0 + wn * 64 + n * 16 + lr;
        float v0 = acc0[m][n][j] * rs[m][j] * sw0;
        float o;
        if constexpr (DUAL) {
          float v1 = acc1[m][n][j] * rs[m][j] * sw1;
          o = v1 / (1.f + expf(-v0));  // sigmoid(gate) * up
        } else {
          o = v0;
        }
        C[(size_t)row * N + col] = o;
      }
}

extern "C" void kernel_launch(void* const* d_in, const int* in_sizes, int n_in,
                              void* d_out, int out_size, void* d_ws, size_t ws_size,
                              hipStream_t stream) {
  const float* x  = (const float*)d_in[0];
  const float* wg = (const float*)d_in[1];
  const float* wu = (const float*)d_in[2];
  const float* wd = (const float*)d_in[3];
  float* out = (float*)d_out;
  char* ws = (char*)d_ws;

  double* dsum = (double*)(ws + OFF_DSUM);
  float* sx = (float*)(ws + OFF_SX);
  float* sh = (float*)(ws + OFF_SH);
  __bf16* xq  = (__bf16*)(ws + OFF_XQ);
  __bf16* wgq = (__bf16*)(ws + OFF_WGQ);
  __bf16* wuq = (__bf16*)(ws + OFF_WUQ);
  __bf16* wdq = (__bf16*)(ws + OFF_WDQ);

  // strip size adapts to available workspace: per row need 8192*4 (h fp32)
  // + 8192*2 (hq bf16) = 48KB
  size_t avail = ws_size > FIXED_END ? ws_size - FIXED_END : 0;
  int S = 128;
  for (int cand = 8192; cand >= 128; cand >>= 1) {
    if ((size_t)cand * 49152ull <= avail) { S = cand; break; }
  }
  float*  hbuf = (float*)(ws + FIXED_END);
  __bf16* hqbuf = (__bf16*)(ws + FIXED_END + (size_t)S * DF * 4);

  hipMemsetAsync(ws, 0, 64, stream);

  const int n4 = NW / 4;
  k_wabs<<<2048, 256, 0, stream>>>(wg, dsum + 0, n4);
  k_wabs<<<2048, 256, 0, stream>>>(wu, dsum + 1, n4);
  k_wabs<<<2048, 256, 0, stream>>>(wd, dsum + 2, n4);

  k_quant_w<<<2048, 256, 0, stream>>>(wg, wgq, dsum + 0, n4);
  k_quant_w<<<2048, 256, 0, stream>>>(wu, wuq, dsum + 1, n4);
  k_quant_w<<<2048, 256, 0, stream>>>(wd, wdq, dsum + 2, n4);

  k_quant_x<<<TOK, 256, 0, stream>>>(x, xq, sx);

  for (int base = 0; base < TOK; base += S) {
    k_gemm<1><<<dim3(DF / 128, S / 128), 256, 0, stream>>>(
        xq + (size_t)base * DM, wgq, wuq, hbuf, sx + base,
        dsum + 0, dsum + 1, DF, DM);

    k_hquant<<<S, 256, 0, stream>>>(hbuf, hqbuf, sh + base);

    k_gemm<0><<<dim3(DM / 128, S / 128), 256, 0, stream>>>(
        hqbuf, wdq, nullptr, out + (size_t)base * DM, sh + base,
        dsum + 2, dsum + 2, DM, DF);
  }
}